// Round 1
// baseline (1478.259 us; speedup 1.0000x reference)
//
#include <hip/hip_runtime.h>
#include <math.h>

// FNO1d: B=64, C_IN=1, N=8192, WIDTH=64, MODES=16, NLAYERS=4
// Only 16 Fourier modes are used -> replace FFTs with partial DFT GEMMs.
//
// ws layout (floats):
//   h     : B*W*N          = 33,554,432   (single buffer, layers update in place)
//   S     : B*W*16*2       = 131,072      (forward DFT modes, complex interleaved)
//   M     : B*W*16*2       = 131,072      (mixed modes)
//   trig2 : N*2            = 16,384       (cos,sin interleaved table)
// total ~129.2 MB

#define BB 64
#define WW 64
#define NN 8192
#define MODES 16
#define NL 4

#define HS_STRIDE 140   // 128 data floats + 4-float pad every 32 -> 2-way conflicts only

__device__ __forceinline__ int hs_col(int c) { return c + ((c >> 5) << 2); }

// ---------------------------------------------------------------- trig table
__global__ __launch_bounds__(256) void fill_trig(float* __restrict__ trig2) {
    int n = blockIdx.x * 256 + threadIdx.x;
    float s, c;
    sincospif(2.0f * (float)n / 8192.0f, &s, &c);   // angle = 2*pi*n/N
    trig2[2 * n]     = c;
    trig2[2 * n + 1] = s;
}

// ---------------------------------------------------------------- lifting
// h[b,w,n] = p_w[w,0]*x[b,n] + p_w[w,1]*grid[n] + p_b[w],  grid[n]=n/8191
__global__ __launch_bounds__(256) void lift_kernel(const float* __restrict__ x,
                                                   const float* __restrict__ p_w,
                                                   const float* __restrict__ p_b,
                                                   float* __restrict__ h) {
    int idx = blockIdx.x * 256 + threadIdx.x;        // over B*N
    int b = idx >> 13, n = idx & (NN - 1);
    float xv = x[idx];
    float g = (float)n * (1.0f / 8191.0f);
    size_t base = ((size_t)(b * WW) << 13);
#pragma unroll 4
    for (int w = 0; w < WW; ++w) {
        h[base + ((size_t)w << 13) + n] = p_w[2 * w] * xv + p_w[2 * w + 1] * g + p_b[w];
    }
}

// ---------------------------------------------------------------- forward partial DFT
// S[b,i,k] += sum_{n in tile} h[b,i,n] * (cos, -sin)(2*pi*k*n/N), k<16
// block = (b, ntile of 128), 256 threads; per-thread tile 4i x (1k x {re,im})
__global__ __launch_bounds__(256) void fwd_dft_kernel(const float* __restrict__ h,
                                                      const float* __restrict__ trig2,
                                                      float* __restrict__ S) {
    __shared__ float Hs[64 * HS_STRIDE];   // 35840 B
    __shared__ float BasT[128 * 34];       // 17408 B  BasT[n][2k+ri], ri0=cos ri1=-sin
    int t = threadIdx.x;
    int b = blockIdx.x >> 6;
    int ntile = blockIdx.x & 63;
    int n0 = ntile << 7;
    const float* hb = h + (((size_t)(b * WW)) << 13) + n0;

#pragma unroll
    for (int r = 0; r < 8; ++r) {          // stage 64x128 h tile (float4, coalesced)
        int v = t + 256 * r;
        int i = v >> 5, c4 = v & 31;
        float4 val = *(const float4*)(hb + ((size_t)i << 13) + (c4 << 2));
        *(float4*)&Hs[i * HS_STRIDE + hs_col(c4 << 2)] = val;
    }
#pragma unroll
    for (int q = 0; q < 16; ++q) {         // stage transposed basis
        int v = t + 256 * q;               // 4096 entries
        int n = v >> 5, r = v & 31;
        int k = r >> 1;
        int idx = (k * (n0 + n)) & (NN - 1);
        float c = trig2[2 * idx], s = trig2[2 * idx + 1];
        BasT[n * 34 + r] = (r & 1) ? -s : c;
    }
    __syncthreads();

    int ig = t >> 4;        // 16 groups x 4 rows i
    int kg = t & 15;        // k = kg, two outputs: re, im
    int i0 = ig << 2;
    float accR[4] = {0.f, 0.f, 0.f, 0.f};
    float accI[4] = {0.f, 0.f, 0.f, 0.f};

#pragma unroll 4
    for (int n4 = 0; n4 < 32; ++n4) {
        int pc = hs_col(n4 << 2);
        float4 a0 = *(const float4*)&Hs[(i0 + 0) * HS_STRIDE + pc];
        float4 a1 = *(const float4*)&Hs[(i0 + 1) * HS_STRIDE + pc];
        float4 a2 = *(const float4*)&Hs[(i0 + 2) * HS_STRIDE + pc];
        float4 a3 = *(const float4*)&Hs[(i0 + 3) * HS_STRIDE + pc];
        float2 b0 = *(const float2*)&BasT[(n4 * 4 + 0) * 34 + 2 * kg];
        float2 b1 = *(const float2*)&BasT[(n4 * 4 + 1) * 34 + 2 * kg];
        float2 b2 = *(const float2*)&BasT[(n4 * 4 + 2) * 34 + 2 * kg];
        float2 b3 = *(const float2*)&BasT[(n4 * 4 + 3) * 34 + 2 * kg];
        float av0[4] = {a0.x, a0.y, a0.z, a0.w};
        float av1[4] = {a1.x, a1.y, a1.z, a1.w};
        float av2[4] = {a2.x, a2.y, a2.z, a2.w};
        float av3[4] = {a3.x, a3.y, a3.z, a3.w};
        float bc[4] = {b0.x, b1.x, b2.x, b3.x};
        float bs[4] = {b0.y, b1.y, b2.y, b3.y};
#pragma unroll
        for (int d = 0; d < 4; ++d) {
            accR[0] += av0[d] * bc[d];  accI[0] += av0[d] * bs[d];
            accR[1] += av1[d] * bc[d];  accI[1] += av1[d] * bs[d];
            accR[2] += av2[d] * bc[d];  accI[2] += av2[d] * bs[d];
            accR[3] += av3[d] * bc[d];  accI[3] += av3[d] * bs[d];
        }
    }
#pragma unroll
    for (int ii = 0; ii < 4; ++ii) {
        int base = ((b * 64 + i0 + ii) * 16 + kg) * 2;
        atomicAdd(&S[base + 0], accR[ii]);
        atomicAdd(&S[base + 1], accI[ii]);
    }
}

// ---------------------------------------------------------------- mode mixing
// M[b,o,k] = sum_i S[b,i,k] * (wr + j*wi)[i,o,k]
__global__ __launch_bounds__(256) void mode_mix_kernel(const float* __restrict__ S,
                                                       const float* __restrict__ wr,
                                                       const float* __restrict__ wi,
                                                       float* __restrict__ M) {
    int b = blockIdx.x, t = threadIdx.x;
    __shared__ float Ss[2048];
#pragma unroll
    for (int q = 0; q < 8; ++q) Ss[t + 256 * q] = S[b * 2048 + t + 256 * q];
    __syncthreads();
#pragma unroll
    for (int q = 0; q < 4; ++q) {
        int out = q * 256 + t;     // o*16 + k
        int o = out >> 4, k = out & 15;
        float aR = 0.f, aI = 0.f;
#pragma unroll 4
        for (int i = 0; i < 64; ++i) {
            float sr = Ss[i * 32 + 2 * k], si = Ss[i * 32 + 2 * k + 1];
            float wrv = wr[(i * 64 + o) * 16 + k];
            float wiv = wi[(i * 64 + o) * 16 + k];
            aR += sr * wrv - si * wiv;
            aI += sr * wiv + si * wrv;
        }
        M[b * 2048 + o * 32 + 2 * k]     = aR;
        M[b * 2048 + o * 32 + 2 * k + 1] = aI;
    }
}

// ---------------------------------------------------------------- fused layer (in place)
// h[b,o,n] = gelu( sum_i Wl[o,i]*h[b,i,n] + bl[o] + irfft16(M)[b,o,n] )
// block = (b, ntile of 128); per-thread tile 4o x 8n
__global__ __launch_bounds__(256) void layer_kernel(float* __restrict__ h,
                                                    const float* __restrict__ Wl,
                                                    const float* __restrict__ bl,
                                                    const float* __restrict__ M,
                                                    const float* __restrict__ trig2) {
    __shared__ float Hs[64 * HS_STRIDE];   // 35840 B
    __shared__ float Wt[64 * 64];          // 16384 B   Wt[i][o]
    __shared__ float Ms[64 * 34];          // 8704 B    Ms[o][2k+ri] pre-scaled
    int t = threadIdx.x;
    int b = blockIdx.x >> 6;
    int ntile = blockIdx.x & 63;
    int n0 = ntile << 7;
    float* hb = h + (((size_t)(b * WW)) << 13) + n0;

#pragma unroll
    for (int r = 0; r < 8; ++r) {          // stage h tile
        int v = t + 256 * r;
        int i = v >> 5, c4 = v & 31;
        float4 val = *(const float4*)(hb + ((size_t)i << 13) + (c4 << 2));
        *(float4*)&Hs[i * HS_STRIDE + hs_col(c4 << 2)] = val;
    }
#pragma unroll
    for (int q = 0; q < 16; ++q) {         // stage W transposed (LDS-coalesced writes)
        int v = t + 256 * q;
        int i = v >> 6, o = v & 63;
        Wt[i * 64 + o] = Wl[o * 64 + i];
    }
#pragma unroll
    for (int q = 0; q < 8; ++q) {          // stage modes, scaled: re: s_k*Mr, im: -s_k*Mi
        int v = t + 256 * q;               // 2048
        int o = v >> 5, c = v & 31;
        int k = c >> 1;
        float raw = M[b * 2048 + o * 32 + c];
        float sc = (k == 0 ? 1.0f : 2.0f) * (1.0f / 8192.0f);
        Ms[o * 34 + c] = (c & 1) ? -sc * raw : sc * raw;
    }
    __syncthreads();

    int ng = t & 15;           // n sub-tile: 8 consecutive
    int og = t >> 4;           // o sub-tile: 4 consecutive
    int nl = ng << 3;
    int o0 = og << 2;
    float acc[4][8] = {};

    // pointwise conv GEMM over 64 input channels
    int pc = hs_col(nl);       // nl is a multiple of 8 -> 8 floats contiguous in padded layout
#pragma unroll 2
    for (int i = 0; i < 64; ++i) {
        float4 wv = *(const float4*)&Wt[(i << 6) + o0];
        float4 h0 = *(const float4*)&Hs[i * HS_STRIDE + pc];
        float4 h1 = *(const float4*)&Hs[i * HS_STRIDE + pc + 4];
        float wvs[4] = {wv.x, wv.y, wv.z, wv.w};
        float hv[8] = {h0.x, h0.y, h0.z, h0.w, h1.x, h1.y, h1.z, h1.w};
#pragma unroll
        for (int oo = 0; oo < 4; ++oo)
#pragma unroll
            for (int d = 0; d < 8; ++d) acc[oo][d] += wvs[oo] * hv[d];
    }

    // inverse DFT of 16 modes via phasor rotation (k=0 phasor = (1,0))
    float cn[8], sn[8], cb[8], sb[8];
#pragma unroll
    for (int d = 0; d < 8; ++d) {
        int n = n0 + nl + d;
        cb[d] = trig2[2 * n];
        sb[d] = trig2[2 * n + 1];
        cn[d] = 1.0f;
        sn[d] = 0.0f;
    }
#pragma unroll
    for (int k = 0; k < MODES; ++k) {
#pragma unroll
        for (int oo = 0; oo < 4; ++oo) {
            float2 m = *(const float2*)&Ms[(o0 + oo) * 34 + 2 * k];
#pragma unroll
            for (int d = 0; d < 8; ++d) acc[oo][d] += m.x * cn[d] + m.y * sn[d];
        }
#pragma unroll
        for (int d = 0; d < 8; ++d) {      // rotate phasor by 2*pi*n/N
            float c2 = cn[d] * cb[d] - sn[d] * sb[d];
            float s2 = sn[d] * cb[d] + cn[d] * sb[d];
            cn[d] = c2;
            sn[d] = s2;
        }
    }

    // bias + exact GELU + in-place store (this block owns exactly this region)
#pragma unroll
    for (int oo = 0; oo < 4; ++oo) {
        float bias = bl[o0 + oo];
        float res[8];
#pragma unroll
        for (int d = 0; d < 8; ++d) {
            float v = acc[oo][d] + bias;
            res[d] = 0.5f * v * (1.0f + erff(v * 0.70710678118654752f));
        }
        float4 r0 = {res[0], res[1], res[2], res[3]};
        float4 r1 = {res[4], res[5], res[6], res[7]};
        float* dst = hb + ((size_t)(o0 + oo) << 13) + nl;
        *(float4*)(dst)     = r0;
        *(float4*)(dst + 4) = r1;
    }
}

// ---------------------------------------------------------------- projection
__global__ __launch_bounds__(256) void proj_kernel(const float* __restrict__ h,
                                                   const float* __restrict__ q_w,
                                                   const float* __restrict__ q_b,
                                                   float* __restrict__ out) {
    int idx = blockIdx.x * 256 + threadIdx.x;   // B*N
    int b = idx >> 13, n = idx & (NN - 1);
    const float* hb = h + (((size_t)(b * WW)) << 13) + n;
    float acc = q_b[0];
#pragma unroll 8
    for (int o = 0; o < WW; ++o) acc += q_w[o] * hb[(size_t)o << 13];
    out[idx] = acc;
}

// ---------------------------------------------------------------- launch
extern "C" void kernel_launch(void* const* d_in, const int* in_sizes, int n_in,
                              void* d_out, int out_size, void* d_ws, size_t ws_size,
                              hipStream_t stream) {
    const float* x     = (const float*)d_in[0];
    const float* p_w   = (const float*)d_in[1];
    const float* p_b   = (const float*)d_in[2];
    const float* sc_wr = (const float*)d_in[3];
    const float* sc_wi = (const float*)d_in[4];
    const float* w_w   = (const float*)d_in[5];
    const float* w_b   = (const float*)d_in[6];
    const float* q_w   = (const float*)d_in[7];
    const float* q_b   = (const float*)d_in[8];
    float* out = (float*)d_out;

    float* h     = (float*)d_ws;                        // 33,554,432 floats
    float* S     = h + (size_t)BB * WW * NN;            // 131,072
    float* M     = S + (size_t)BB * WW * MODES * 2;     // 131,072
    float* trig2 = M + (size_t)BB * WW * MODES * 2;     // 16,384
    // total ws: ~129.2 MB

    hipLaunchKernelGGL(fill_trig, dim3(NN / 256), dim3(256), 0, stream, trig2);
    hipLaunchKernelGGL(lift_kernel, dim3(BB * NN / 256), dim3(256), 0, stream, x, p_w, p_b, h);
    for (int l = 0; l < NL; ++l) {
        hipMemsetAsync(S, 0, (size_t)BB * WW * MODES * 2 * sizeof(float), stream);
        hipLaunchKernelGGL(fwd_dft_kernel, dim3(BB * 64), dim3(256), 0, stream, h, trig2, S);
        hipLaunchKernelGGL(mode_mix_kernel, dim3(BB), dim3(256), 0, stream,
                           S, sc_wr + l * 65536, sc_wi + l * 65536, M);
        hipLaunchKernelGGL(layer_kernel, dim3(BB * 64), dim3(256), 0, stream,
                           h, w_w + l * 4096, w_b + l * 64, M, trig2);
    }
    hipLaunchKernelGGL(proj_kernel, dim3(BB * NN / 256), dim3(256), 0, stream, h, q_w, q_b, out);
}

// Round 3
// 414.197 us; speedup vs baseline: 3.5690x; 3.5690x over previous
//
#include <hip/hip_runtime.h>
#include <math.h>

// FNO1d via fp16 MFMA. B=64, W=64, N=8192, MODES=16, 4 layers.
// - h stored fp16 channel-first [b][i][n] (67 MB)
// - pointwise conv AND 16-mode irfft are both 16x16x32_f16 MFMA GEMMs into the
//   same accumulators; forward partial DFT of the produced tile is a third MFMA
//   fused in the epilogue (atomicAdd fp32 into S). proj fused into layer 3.
// Layout (verified m89/m91): A[m=lane&15][k=quad*8+j], B[k=quad*8+j][n=lane&15],
// C/D col=lane&15, row=quad*4+reg.
//
// R2 bugfix: Ht/Hout are [64][128] tiles -> strides must be >=128 halfs
// (were 68/72: row overflow). HT_S=132, HO_S=136. Hout aliases Ht+Ws pool
// (epilogue writes only after the sync ending all Ht/Ws reads).

typedef _Float16 f16;
typedef _Float16 f16x8 __attribute__((ext_vector_type(8)));
typedef _Float16 f16x4 __attribute__((ext_vector_type(4)));
typedef float    f32x4 __attribute__((ext_vector_type(4)));

#define BB 64
#define NN 8192

#define HT_S 132   // Ht [i=64][n=128]: 264B rows (8B-aligned b64 staging)
#define HO_S 136   // Hout [o=64][n=128]: 272B rows (16B-aligned b128 reads)
#define WS_S 72    // Ws [o=64][i=64]
#define MS_S 40    // Ms2 [o=64][j=32]
#define BI_S 40    // BasI [n=128][j=32]
#define BF_S 136   // BasF [km=32][n=128]

// ---------------------------------------------------------------- basis fill
// BasF[k][n]=cos(2pi k n/N), BasF[16+k][n]=-sin  (forward DFT rows)
// BasI[n][2k]=cos, [2k+1]=sin                    (inverse DFT columns)
__global__ __launch_bounds__(256) void fill_basis(f16* __restrict__ basF,
                                                  f16* __restrict__ basI) {
    int n = blockIdx.x * 256 + threadIdx.x;
    f16 row[32];
#pragma unroll
    for (int k = 0; k < 16; ++k) {
        float s, c;
        sincospif((float)(k * n) * (1.0f / 4096.0f), &s, &c);  // angle/pi = 2kn/N
        basF[k * NN + n]        = (f16)c;
        basF[(16 + k) * NN + n] = (f16)(-s);
        row[2 * k]     = (f16)c;
        row[2 * k + 1] = (f16)s;
    }
#pragma unroll
    for (int q = 0; q < 4; ++q) *(f16x8*)&basI[n * 32 + 8 * q] = *(f16x8*)&row[8 * q];
}

// ---------------------------------------------------------------- mode mixing
// reads S[b][km 32][i 64] (km<16: Re, km>=16: Im), writes pre-scaled
// Mp[b][o][2k]=sck*(Re.wr - Im.wi), Mp[b][o][2k+1]=-sck*(Re.wi + Im.wr)
__global__ __launch_bounds__(256) void mode_mix(const float* __restrict__ S,
                                                const float* __restrict__ wr,
                                                const float* __restrict__ wi,
                                                float* __restrict__ Mp) {
    int b = blockIdx.x, t = threadIdx.x;
    __shared__ float Ss[32 * 66];
#pragma unroll
    for (int r = 0; r < 8; ++r) {
        int v = t + 256 * r;
        Ss[(v >> 6) * 66 + (v & 63)] = S[b * 2048 + v];
    }
    __syncthreads();
#pragma unroll
    for (int it = 0; it < 4; ++it) {
        int p = it * 256 + t;      // o*16 + k
        int o = p >> 4, k = p & 15;
        float ar = 0.f, ai = 0.f;
#pragma unroll 4
        for (int i = 0; i < 64; ++i) {
            float sr = Ss[k * 66 + i], si = Ss[(16 + k) * 66 + i];
            float wrv = wr[(i * 64 + o) * 16 + k];
            float wiv = wi[(i * 64 + o) * 16 + k];
            ar += sr * wrv - si * wiv;
            ai += sr * wiv + si * wrv;
        }
        float sc = (k == 0 ? 1.0f : 2.0f) * (1.0f / 8192.0f);
        Mp[b * 2048 + o * 32 + 2 * k]     = sc * ar;
        Mp[b * 2048 + o * 32 + 2 * k + 1] = -sc * ai;
    }
}

// ---------------------------------------------------------------- DFT epilogue (shared)
// S[b][km][i] += BasF[km][n] . Hout[i][n]  over this block's 128-n tile
__device__ __forceinline__ void dft_epilogue(const f16* Hout, const f16* BasF,
                                             float* __restrict__ S, int b,
                                             int lane, int wv) {
    int q = lane >> 4, l15 = lane & 15;
    f32x4 sacc[2] = {{0.f,0.f,0.f,0.f},{0.f,0.f,0.f,0.f}};
#pragma unroll
    for (int ks = 0; ks < 4; ++ks) {
        int o = (wv << 4) + l15;
        f16x8 bh = *(const f16x8*)&Hout[o * HO_S + ks * 32 + q * 8];
#pragma unroll
        for (int mt = 0; mt < 2; ++mt) {
            f16x8 af = *(const f16x8*)&BasF[(mt * 16 + l15) * BF_S + ks * 32 + q * 8];
            sacc[mt] = __builtin_amdgcn_mfma_f32_16x16x32_f16(af, bh, sacc[mt], 0, 0, 0);
        }
    }
#pragma unroll
    for (int mt = 0; mt < 2; ++mt)
#pragma unroll
        for (int r = 0; r < 4; ++r)
            atomicAdd(&S[(b * 32 + mt * 16 + q * 4 + r) * 64 + (wv << 4) + l15],
                      sacc[mt][r]);
}

__device__ __forceinline__ void stage_basF(f16* BasF, const f16* __restrict__ basF_g,
                                           int n0, int t) {
#pragma unroll
    for (int u = 0; u < 2; ++u) {
        int km = t >> 3, nn = (t & 7) * 16 + u * 8;
        *(f16x8*)&BasF[km * BF_S + nn] = *(const f16x8*)&basF_g[km * NN + n0 + nn];
    }
}

// ---------------------------------------------------------------- lifting (+DFT)
__global__ __launch_bounds__(256, 3) void lift_kernel(const float* __restrict__ x,
                                                      const float* __restrict__ p_w,
                                                      const float* __restrict__ p_b,
                                                      f16* __restrict__ h,
                                                      const f16* __restrict__ basF_g,
                                                      float* __restrict__ S) {
    __shared__ f16 Hout[64 * HO_S];
    __shared__ f16 BasF[32 * BF_S];
    int t = threadIdx.x;
    int b = blockIdx.x >> 6;
    int n0 = (blockIdx.x & 63) << 7;
#pragma unroll
    for (int r = 0; r < 4; ++r) {
        int o = (t >> 4) + 16 * r;
        int ns = (t & 15) << 3;
        float w0 = p_w[2 * o], w1 = p_w[2 * o + 1], pb = p_b[o];
        f16 vals[8];
#pragma unroll
        for (int j = 0; j < 8; ++j) {
            int n = n0 + ns + j;
            float xv = x[(b << 13) + n];
            vals[j] = (f16)(w0 * xv + w1 * ((float)n * (1.0f / 8191.0f)) + pb);
        }
        *(f16x8*)&Hout[o * HO_S + ns] = *(f16x8*)vals;
        *(f16x8*)(h + (((size_t)(b * 64 + o)) << 13) + n0 + ns) = *(f16x8*)vals;
    }
    stage_basF(BasF, basF_g, n0, t);
    __syncthreads();
    dft_epilogue(Hout, BasF, S, b, t & 63, t >> 6);
}

// ---------------------------------------------------------------- fused layer
// DO_DFT=1: layers 0..2 (write h + accumulate S). DO_DFT=0: layer 3 (proj -> out)
template <int DO_DFT>
__global__ __launch_bounds__(256, 3) void layer_kernel(f16* __restrict__ h,
                                                       const float* __restrict__ Wl,
                                                       const float* __restrict__ bl,
                                                       const float* __restrict__ Mp,
                                                       const f16* __restrict__ basF_g,
                                                       const f16* __restrict__ basI_g,
                                                       float* __restrict__ S,
                                                       const float* __restrict__ q_w,
                                                       const float* __restrict__ q_b,
                                                       float* __restrict__ out) {
    // pool: Ht[64*HT_S] (16896B) + Ws[64*WS_S] (9216B); Hout (17408B) aliases it
    __shared__ __align__(16) char pool[16896 + 9216];
    f16* Ht   = (f16*)pool;
    f16* Ws   = (f16*)(pool + 16896);
    f16* Hout = (f16*)pool;
    __shared__ f16 Ms2[64 * MS_S];
    __shared__ f16 BasI[128 * BI_S];
    __shared__ f16 BasF[32 * BF_S];
    __shared__ float bls[64];
    int t = threadIdx.x;
    int b = blockIdx.x >> 6;
    int n0 = (blockIdx.x & 63) << 7;
    f16* hb = h + (((size_t)(b * 64)) << 13) + n0;

    // ---- stage Ht [i][n]
#pragma unroll
    for (int r = 0; r < 4; ++r) {
        int i = (t >> 4) + 16 * r;
        int ns = (t & 15) << 3;
        f16x8 v = *(const f16x8*)(hb + ((size_t)i << 13) + ns);
        f16x4 lo = {v[0], v[1], v[2], v[3]}, hi = {v[4], v[5], v[6], v[7]};
        *(f16x4*)&Ht[i * HT_S + ns]     = lo;    // b64: rows 8B-aligned
        *(f16x4*)&Ht[i * HT_S + ns + 4] = hi;
    }
    // ---- stage Ws [o][i] fp16
#pragma unroll
    for (int r = 0; r < 4; ++r) {
        int flat = (r * 256 + t) * 4;
        int o = flat >> 6, i = flat & 63;
        float4 wv = *(const float4*)&Wl[flat];
        f16x4 wh = {(f16)wv.x, (f16)wv.y, (f16)wv.z, (f16)wv.w};
        *(f16x4*)&Ws[o * WS_S + i] = wh;
    }
    // ---- stage Ms2 [o][j]
#pragma unroll
    for (int r = 0; r < 2; ++r) {
        int flat = (r * 256 + t) * 4;
        int o = flat >> 5, j = flat & 31;
        float4 mv = *(const float4*)&Mp[b * 2048 + flat];
        f16x4 mh = {(f16)mv.x, (f16)mv.y, (f16)mv.z, (f16)mv.w};
        *(f16x4*)&Ms2[o * MS_S + j] = mh;
    }
    // ---- stage BasI [n][j]
    {
        int n = t >> 1, jc = (t & 1) * 16;
        *(f16x8*)&BasI[n * BI_S + jc]     = *(const f16x8*)&basI_g[(n0 + n) * 32 + jc];
        *(f16x8*)&BasI[n * BI_S + jc + 8] = *(const f16x8*)&basI_g[(n0 + n) * 32 + jc + 8];
    }
    if (DO_DFT) stage_basF(BasF, basF_g, n0, t);
    if (t < 64) bls[t] = bl[t];
    __syncthreads();

    int lane = t & 63, wv = t >> 6;
    int q = lane >> 4, l15 = lane & 15;

    // ---- conv GEMM: D[o][n] = W[o][i] . h[i][n], K=64 (2 ksteps)
    f16x8 Af[4][2];
#pragma unroll
    for (int mt = 0; mt < 4; ++mt)
#pragma unroll
        for (int ks = 0; ks < 2; ++ks)
            Af[mt][ks] = *(const f16x8*)&Ws[(mt * 16 + l15) * WS_S + ks * 32 + q * 8];

    f32x4 acc[4][2];
#pragma unroll
    for (int mt = 0; mt < 4; ++mt)
#pragma unroll
        for (int c = 0; c < 2; ++c) acc[mt][c] = (f32x4){0.f, 0.f, 0.f, 0.f};

#pragma unroll
    for (int ct2 = 0; ct2 < 2; ++ct2) {
        int n = ((2 * wv + ct2) << 4) + l15;
#pragma unroll
        for (int ks = 0; ks < 2; ++ks) {
            f16x8 bf;
#pragma unroll
            for (int j = 0; j < 8; ++j) bf[j] = Ht[(ks * 32 + q * 8 + j) * HT_S + n];
#pragma unroll
            for (int mt = 0; mt < 4; ++mt)
                acc[mt][ct2] = __builtin_amdgcn_mfma_f32_16x16x32_f16(
                    Af[mt][ks], bf, acc[mt][ct2], 0, 0, 0);
        }
    }
    // ---- irfft GEMM: += Ms2[o][j] . BasI[n][j], K=32 (1 kstep)
    f16x8 Mf[4];
#pragma unroll
    for (int mt = 0; mt < 4; ++mt)
        Mf[mt] = *(const f16x8*)&Ms2[(mt * 16 + l15) * MS_S + q * 8];
#pragma unroll
    for (int ct2 = 0; ct2 < 2; ++ct2) {
        f16x8 bi = *(const f16x8*)&BasI[(((2 * wv + ct2) << 4) + l15) * BI_S + q * 8];
#pragma unroll
        for (int mt = 0; mt < 4; ++mt)
            acc[mt][ct2] = __builtin_amdgcn_mfma_f32_16x16x32_f16(
                Mf[mt], bi, acc[mt][ct2], 0, 0, 0);
    }

    // ---- epilogue: bias + exact GELU -> Hout [o][n] fp16 (Hout aliases Ht/Ws!)
    __syncthreads();   // all Ht/Ws reads complete before overwrite
#pragma unroll
    for (int mt = 0; mt < 4; ++mt)
#pragma unroll
        for (int ct2 = 0; ct2 < 2; ++ct2) {
            int n = ((2 * wv + ct2) << 4) + l15;
#pragma unroll
            for (int r = 0; r < 4; ++r) {
                int o = mt * 16 + q * 4 + r;
                float v = acc[mt][ct2][r] + bls[o];
                float g = 0.5f * v * (1.0f + erff(v * 0.70710678118654752f));
                Hout[o * HO_S + n] = (f16)g;
            }
        }
    __syncthreads();

    if (DO_DFT) {
        dft_epilogue(Hout, BasF, S, b, lane, wv);
        // ---- store h tile (coalesced b128)
#pragma unroll
        for (int r = 0; r < 4; ++r) {
            int o = (t >> 4) + 16 * r;
            int ns = (t & 15) << 3;
            *(f16x8*)(hb + ((size_t)o << 13) + ns) = *(f16x8*)&Hout[o * HO_S + ns];
        }
    } else {
        // ---- projection: out[b][n] = q_b + sum_o q_w[o]*h[o][n]
        if (t < 128) {
            int n = t;
            float s = q_b[0];
#pragma unroll 8
            for (int o = 0; o < 64; ++o) s += q_w[o] * (float)Hout[o * HO_S + n];
            out[(b << 13) + n0 + n] = s;
        }
    }
}

// ---------------------------------------------------------------- launch
extern "C" void kernel_launch(void* const* d_in, const int* in_sizes, int n_in,
                              void* d_out, int out_size, void* d_ws, size_t ws_size,
                              hipStream_t stream) {
    const float* x     = (const float*)d_in[0];
    const float* p_w   = (const float*)d_in[1];
    const float* p_b   = (const float*)d_in[2];
    const float* sc_wr = (const float*)d_in[3];
    const float* sc_wi = (const float*)d_in[4];
    const float* w_w   = (const float*)d_in[5];
    const float* w_b   = (const float*)d_in[6];
    const float* q_w   = (const float*)d_in[7];
    const float* q_b   = (const float*)d_in[8];
    float* out = (float*)d_out;

    char* ws = (char*)d_ws;
    f16*   h    = (f16*)ws;                                  // 67,108,864 B
    float* S    = (float*)(ws + (size_t)67108864);           // 524,288 B
    float* Mp   = (float*)(ws + (size_t)67108864 + 524288);  // 524,288 B
    f16*   basF = (f16*)(ws + (size_t)67108864 + 1048576);   // 524,288 B
    f16*   basI = (f16*)(ws + (size_t)67108864 + 1572864);   // 524,288 B

    hipLaunchKernelGGL(fill_basis, dim3(NN / 256), dim3(256), 0, stream, basF, basI);
    hipMemsetAsync(S, 0, 524288, stream);
    hipLaunchKernelGGL(lift_kernel, dim3(BB * 64), dim3(256), 0, stream,
                       x, p_w, p_b, h, basF, S);
    for (int l = 0; l < 4; ++l) {
        hipLaunchKernelGGL(mode_mix, dim3(BB), dim3(256), 0, stream,
                           S, sc_wr + l * 65536, sc_wi + l * 65536, Mp);
        if (l < 3) {
            hipMemsetAsync(S, 0, 524288, stream);
            hipLaunchKernelGGL((layer_kernel<1>), dim3(BB * 64), dim3(256), 0, stream,
                               h, w_w + l * 4096, w_b + l * 64, Mp, basF, basI, S,
                               q_w, q_b, out);
        } else {
            hipLaunchKernelGGL((layer_kernel<0>), dim3(BB * 64), dim3(256), 0, stream,
                               h, w_w + l * 4096, w_b + l * 64, Mp, basF, basI, S,
                               q_w, q_b, out);
        }
    }
}

// Round 5
// 395.468 us; speedup vs baseline: 3.7380x; 1.0474x over previous
//
#include <hip/hip_runtime.h>
#include <math.h>

// FNO1d via fp16 MFMA, round 5: role-swapped GEMM (m=n-dim, col=o-dim).
// - Ht staged transposed [n][i] via in-register 8x8 v_perm transposes with
//   XOR bank swizzle (stride 64, no pad) -> A-frags are single ds_read_b128.
// - Epilogue: lane holds 4 consecutive n at fixed o -> v_cvt_pkrtz pairs +
//   b64 LDS writes (was 32 scalar u16 writes + 32 scalar converts).
// - Weights & modes pre-converted to fp16 (prep kernels).
// R4 fix: bit_cast cvt_pkrtz's __fp16x2 result to _Float16x2.
// MFMA layouts (m89/m91): A[m=lane&15][k=quad*8+j], B[k=quad*8+j][n=lane&15],
// C/D col=lane&15, row=quad*4+reg.

typedef _Float16 f16;
typedef _Float16 f16x2 __attribute__((ext_vector_type(2)));
typedef _Float16 f16x4 __attribute__((ext_vector_type(4)));
typedef _Float16 f16x8 __attribute__((ext_vector_type(8)));
typedef float    f32x4 __attribute__((ext_vector_type(4)));
typedef unsigned int u32;

#define BB 64
#define NN 8192

#define HT_S 64    // Ht [n=128][i=64], XOR-swizzled, stride 64 (no pad)
#define HO_S 136   // Hout [o=64][n=128]
#define WS_S 72    // Ws [o=64][i=64]
#define MS_S 40    // Ms2 [o=64][j=32]
#define BI_S 40    // BasI [n=128][j=32]
#define BF_S 136   // BasF [km=32][n=128]

// swizzle group for Ht row n
__device__ __forceinline__ int ht_swz(int n) { return ((n & 7) ^ ((n >> 3) & 7)) << 3; }

// ---------------------------------------------------------------- prep
// BasF[k][n]=cos(2pi k n/N), BasF[16+k][n]=-sin; BasI[n][2k]=cos,[2k+1]=sin
// Also converts w_w (4*64*64) to fp16.
__global__ __launch_bounds__(256) void fill_basis(f16* __restrict__ basF,
                                                  f16* __restrict__ basI,
                                                  const float* __restrict__ w_w,
                                                  f16* __restrict__ Wh) {
    int n = blockIdx.x * 256 + threadIdx.x;   // 0..8191
    f16 row[32];
#pragma unroll
    for (int k = 0; k < 16; ++k) {
        float s, c;
        sincospif((float)(k * n) * (1.0f / 4096.0f), &s, &c);
        basF[k * NN + n]        = (f16)c;
        basF[(16 + k) * NN + n] = (f16)(-s);
        row[2 * k]     = (f16)c;
        row[2 * k + 1] = (f16)s;
    }
#pragma unroll
    for (int q = 0; q < 4; ++q) *(f16x8*)&basI[n * 32 + 8 * q] = *(f16x8*)&row[8 * q];
    Wh[n]        = (f16)w_w[n];
    Wh[n + 8192] = (f16)w_w[n + 8192];
}

// ---------------------------------------------------------------- mode mixing
// S[b][km 32][i 64] (km<16 Re, >=16 Im) -> Mph fp16 pre-scaled:
// Mph[b][o][2k]=sck*(Re.wr - Im.wi), [2k+1]=-sck*(Re.wi + Im.wr)
__global__ __launch_bounds__(256) void mode_mix(const float* __restrict__ S,
                                                const float* __restrict__ wr,
                                                const float* __restrict__ wi,
                                                f16* __restrict__ Mph) {
    int b = blockIdx.x, t = threadIdx.x;
    __shared__ float Ss[32 * 66];
#pragma unroll
    for (int r = 0; r < 8; ++r) {
        int v = t + 256 * r;
        Ss[(v >> 6) * 66 + (v & 63)] = S[b * 2048 + v];
    }
    __syncthreads();
#pragma unroll
    for (int it = 0; it < 4; ++it) {
        int p = it * 256 + t;      // o*16 + k
        int o = p >> 4, k = p & 15;
        float ar = 0.f, ai = 0.f;
#pragma unroll 4
        for (int i = 0; i < 64; ++i) {
            float sr = Ss[k * 66 + i], si = Ss[(16 + k) * 66 + i];
            float wrv = wr[(i * 64 + o) * 16 + k];
            float wiv = wi[(i * 64 + o) * 16 + k];
            ar += sr * wrv - si * wiv;
            ai += sr * wiv + si * wrv;
        }
        float sc = (k == 0 ? 1.0f : 2.0f) * (1.0f / 8192.0f);
        Mph[b * 2048 + o * 32 + 2 * k]     = (f16)(sc * ar);
        Mph[b * 2048 + o * 32 + 2 * k + 1] = (f16)(-sc * ai);
    }
}

// ---------------------------------------------------------------- DFT epilogue
// S[b][km][i] += BasF[km][n] . Hout[i][n]  over this block's 128-n tile
__device__ __forceinline__ void dft_epilogue(const f16* Hout, const f16* BasF,
                                             float* __restrict__ S, int b,
                                             int lane, int wv) {
    int q = lane >> 4, l15 = lane & 15;
    f32x4 sacc[2] = {{0.f,0.f,0.f,0.f},{0.f,0.f,0.f,0.f}};
#pragma unroll
    for (int ks = 0; ks < 4; ++ks) {
        int o = (wv << 4) + l15;
        f16x8 bh = *(const f16x8*)&Hout[o * HO_S + ks * 32 + q * 8];
#pragma unroll
        for (int mt = 0; mt < 2; ++mt) {
            f16x8 af = *(const f16x8*)&BasF[(mt * 16 + l15) * BF_S + ks * 32 + q * 8];
            sacc[mt] = __builtin_amdgcn_mfma_f32_16x16x32_f16(af, bh, sacc[mt], 0, 0, 0);
        }
    }
#pragma unroll
    for (int mt = 0; mt < 2; ++mt)
#pragma unroll
        for (int r = 0; r < 4; ++r)
            atomicAdd(&S[(b * 32 + mt * 16 + q * 4 + r) * 64 + (wv << 4) + l15],
                      sacc[mt][r]);
}

// ---------------------------------------------------------------- lifting (+DFT)
__global__ __launch_bounds__(256, 3) void lift_kernel(const float* __restrict__ x,
                                                      const float* __restrict__ p_w,
                                                      const float* __restrict__ p_b,
                                                      f16* __restrict__ h,
                                                      const f16* __restrict__ basF_g,
                                                      float* __restrict__ S) {
    __shared__ f16 Hout[64 * HO_S];
    __shared__ f16 BasF[32 * BF_S];
    int t = threadIdx.x;
    int b = blockIdx.x >> 6;
    int n0 = (blockIdx.x & 63) << 7;
#pragma unroll
    for (int r = 0; r < 4; ++r) {
        int o = (t >> 4) + 16 * r;
        int ns = (t & 15) << 3;
        float w0 = p_w[2 * o], w1 = p_w[2 * o + 1], pb = p_b[o];
        f16 vals[8];
#pragma unroll
        for (int j = 0; j < 8; ++j) {
            int n = n0 + ns + j;
            float xv = x[(b << 13) + n];
            vals[j] = (f16)(w0 * xv + w1 * ((float)n * (1.0f / 8191.0f)) + pb);
        }
        *(f16x8*)&Hout[o * HO_S + ns] = *(f16x8*)vals;
        *(f16x8*)(h + (((size_t)(b * 64 + o)) << 13) + n0 + ns) = *(f16x8*)vals;
    }
#pragma unroll
    for (int u = 0; u < 2; ++u) {
        int km = t >> 3, nn = (t & 7) * 16 + u * 8;
        *(f16x8*)&BasF[km * BF_S + nn] = *(const f16x8*)&basF_g[km * NN + n0 + nn];
    }
    __syncthreads();
    dft_epilogue(Hout, BasF, S, b, t & 63, t >> 6);
}

// ---------------------------------------------------------------- fused layer
// DO_DFT=1: layers 0..2 (write h + accumulate S). DO_DFT=0: layer 3 (proj)
template <int DO_DFT>
__global__ __launch_bounds__(256, 3) void layer_kernel(f16* __restrict__ h,
                                                       const f16* __restrict__ Wl_h,
                                                       const float* __restrict__ bl,
                                                       const f16* __restrict__ Mph,
                                                       const f16* __restrict__ basF_g,
                                                       const f16* __restrict__ basI_g,
                                                       float* __restrict__ S,
                                                       const float* __restrict__ q_w,
                                                       const float* __restrict__ q_b,
                                                       float* __restrict__ out) {
    // pool: Ht 128*64*2=16384 B + Ws 64*72*2=9216 B; Hout (64*136*2=17408 B) aliases
    __shared__ __align__(16) char pool[16384 + 9216];
    f16* Ht   = (f16*)pool;
    f16* Ws   = (f16*)(pool + 16384);
    f16* Hout = (f16*)pool;
    __shared__ f16 Ms2[64 * MS_S];
    __shared__ f16 BasI[128 * BI_S];
    __shared__ f16 BasF[32 * BF_S];
    __shared__ float bls[64];
    int t = threadIdx.x;
    int b = blockIdx.x >> 6;
    int n0 = (blockIdx.x & 63) << 7;
    f16* hb = h + (((size_t)(b * 64)) << 13) + n0;

    if (t < 128) {
        // ---- transpose-stage Ht[n][i] from global h[i][n] (8x8 blocks)
        int ig = t >> 4, nb = t & 15;       // i0 = ig*8, ns = nb*8
        int i0 = ig << 3, ns = nb << 3;
        f16x8 R[8];
#pragma unroll
        for (int k = 0; k < 8; ++k)
            R[k] = *(const f16x8*)(hb + ((size_t)(i0 + k) << 13) + ns);
        const u32* rd = (const u32*)R;      // rd[k*4 + d]
        int swz = nb & 7;
#pragma unroll
        for (int j = 0; j < 8; ++j) {
            u32 o[4] __attribute__((aligned(16)));
            u32 sel = (j & 1) ? 0x07060302u : 0x05040100u;
            int jd = j >> 1;
#pragma unroll
            for (int e = 0; e < 4; ++e)
                o[e] = __builtin_amdgcn_perm(rd[(2 * e + 1) * 4 + jd],
                                             rd[(2 * e) * 4 + jd], sel);
            int col = i0 ^ ((j ^ swz) << 3);
            *(f16x8*)&Ht[(ns + j) * HT_S + col] = *(const f16x8*)o;
        }
    } else {
        int t2 = t - 128;
        // ---- Ws [o][i] fp16 (pre-converted): 32 halfs per thread
        {
            int o = t2 & 63, hs = (t2 >> 6) * 32;
            const f16* src = Wl_h + o * 64 + hs;
            f16* dst = &Ws[o * WS_S + hs];
#pragma unroll
            for (int u = 0; u < 4; ++u) *(f16x8*)&dst[8 * u] = *(const f16x8*)&src[8 * u];
        }
        // ---- Ms2 [o][j]: 16 halfs per thread
        {
            int o = t2 >> 1, seg = (t2 & 1) * 16;
            const f16* src = Mph + b * 2048 + o * 32 + seg;
            f16* dst = &Ms2[o * MS_S + seg];
            *(f16x8*)&dst[0] = *(const f16x8*)&src[0];
            *(f16x8*)&dst[8] = *(const f16x8*)&src[8];
        }
        // ---- BasI [n][j]: one row per thread
        {
            const f16* src = basI_g + (size_t)(n0 + t2) * 32;
            f16* dst = &BasI[t2 * BI_S];
#pragma unroll
            for (int u = 0; u < 4; ++u) *(f16x8*)&dst[8 * u] = *(const f16x8*)&src[8 * u];
        }
        // ---- BasF [km][n]
        if (DO_DFT) {
            int km = t2 >> 2, seg = (t2 & 3) * 32;
            const f16* src = basF_g + km * NN + n0 + seg;
            f16* dst = &BasF[km * BF_S + seg];
#pragma unroll
            for (int u = 0; u < 4; ++u) *(f16x8*)&dst[8 * u] = *(const f16x8*)&src[8 * u];
        }
    }
    if (t < 64) bls[t] = bl[t];
    __syncthreads();

    int lane = t & 63, wv = t >> 6;
    int q = lane >> 4, l15 = lane & 15;

    // ---- B-frags: Ws (conv) and Ms2 (irfft)
    f16x8 Bw[4][2], Bm[4];
#pragma unroll
    for (int ct = 0; ct < 4; ++ct) {
#pragma unroll
        for (int ks = 0; ks < 2; ++ks)
            Bw[ct][ks] = *(const f16x8*)&Ws[(ct * 16 + l15) * WS_S + ks * 32 + q * 8];
        Bm[ct] = *(const f16x8*)&Ms2[(ct * 16 + l15) * MS_S + q * 8];
    }

    f32x4 acc[4][2];   // [ct(o-tile)][mtl(n-tile)]
#pragma unroll
    for (int ct = 0; ct < 4; ++ct)
#pragma unroll
        for (int m = 0; m < 2; ++m) acc[ct][m] = (f32x4){0.f, 0.f, 0.f, 0.f};

#pragma unroll
    for (int mtl = 0; mtl < 2; ++mtl) {
        int nrow = (2 * wv + mtl) * 16 + l15;
        const f16* hrow = &Ht[nrow * HT_S];
        int g3 = ht_swz(nrow);
        // conv: D[n][o] += h^T[n][i] . W[o][i], K=64
#pragma unroll
        for (int ks = 0; ks < 2; ++ks) {
            f16x8 Ah = *(const f16x8*)&hrow[(ks * 32 + q * 8) ^ g3];
#pragma unroll
            for (int ct = 0; ct < 4; ++ct)
                acc[ct][mtl] = __builtin_amdgcn_mfma_f32_16x16x32_f16(
                    Ah, Bw[ct][ks], acc[ct][mtl], 0, 0, 0);
        }
        // irfft: D[n][o] += BasI[n][j] . Ms2[o][j], K=32
        f16x8 Ab = *(const f16x8*)&BasI[nrow * BI_S + q * 8];
#pragma unroll
        for (int ct = 0; ct < 4; ++ct)
            acc[ct][mtl] = __builtin_amdgcn_mfma_f32_16x16x32_f16(
                Ab, Bm[ct], acc[ct][mtl], 0, 0, 0);
    }

    // ---- epilogue: bias + exact GELU -> Hout[o][n] fp16 (aliases Ht/Ws)
    float bv[4];
#pragma unroll
    for (int ct = 0; ct < 4; ++ct) bv[ct] = bls[ct * 16 + l15];
    __syncthreads();   // all Ht/Ws reads complete before overwrite
#pragma unroll
    for (int ct = 0; ct < 4; ++ct) {
        int o = ct * 16 + l15;
#pragma unroll
        for (int mtl = 0; mtl < 2; ++mtl) {
            int nbase = (2 * wv + mtl) * 16 + q * 4;
            float g[4];
#pragma unroll
            for (int r = 0; r < 4; ++r) {
                float v = acc[ct][mtl][r] + bv[ct];
                g[r] = 0.5f * v * (1.0f + erff(v * 0.70710678118654752f));
            }
            f16x2 lo = __builtin_bit_cast(f16x2, __builtin_amdgcn_cvt_pkrtz(g[0], g[1]));
            f16x2 hi = __builtin_bit_cast(f16x2, __builtin_amdgcn_cvt_pkrtz(g[2], g[3]));
            f16x4 pk = {lo[0], lo[1], hi[0], hi[1]};
            *(f16x4*)&Hout[o * HO_S + nbase] = pk;
        }
    }
    __syncthreads();

    if (DO_DFT) {
        dft_epilogue(Hout, BasF, S, b, lane, wv);
        // ---- store h tile (coalesced b128)
#pragma unroll
        for (int r = 0; r < 4; ++r) {
            int o = (t >> 4) + 16 * r;
            int ns = (t & 15) << 3;
            *(f16x8*)(hb + ((size_t)o << 13) + ns) = *(f16x8*)&Hout[o * HO_S + ns];
        }
    } else {
        // ---- projection: out[b][n] = q_b + sum_o q_w[o]*h[o][n]
        if (t < 128) {
            int n = t;
            float s = q_b[0];
#pragma unroll 8
            for (int o = 0; o < 64; ++o) s += q_w[o] * (float)Hout[o * HO_S + n];
            out[(b << 13) + n0 + n] = s;
        }
    }
}

// ---------------------------------------------------------------- launch
extern "C" void kernel_launch(void* const* d_in, const int* in_sizes, int n_in,
                              void* d_out, int out_size, void* d_ws, size_t ws_size,
                              hipStream_t stream) {
    const float* x     = (const float*)d_in[0];
    const float* p_w   = (const float*)d_in[1];
    const float* p_b   = (const float*)d_in[2];
    const float* sc_wr = (const float*)d_in[3];
    const float* sc_wi = (const float*)d_in[4];
    const float* w_w   = (const float*)d_in[5];
    const float* w_b   = (const float*)d_in[6];
    const float* q_w   = (const float*)d_in[7];
    const float* q_b   = (const float*)d_in[8];
    float* out = (float*)d_out;

    char* ws = (char*)d_ws;
    f16*   h    = (f16*)ws;                               // 67,108,864 B
    float* S    = (float*)(ws + 67108864ull);             // 524,288 B
    f16*   Mph  = (f16*)(ws + 67633152ull);               // 262,144 B
    f16*   basF = (f16*)(ws + 67895296ull);               // 524,288 B
    f16*   basI = (f16*)(ws + 68419584ull);               // 524,288 B
    f16*   Wh   = (f16*)(ws + 68943872ull);               // 32,768 B

    hipLaunchKernelGGL(fill_basis, dim3(NN / 256), dim3(256), 0, stream,
                       basF, basI, w_w, Wh);
    (void)hipMemsetAsync(S, 0, 524288, stream);
    hipLaunchKernelGGL(lift_kernel, dim3(BB * 64), dim3(256), 0, stream,
                       x, p_w, p_b, h, basF, S);
    for (int l = 0; l < 4; ++l) {
        hipLaunchKernelGGL(mode_mix, dim3(BB), dim3(256), 0, stream,
                           S, sc_wr + l * 65536, sc_wi + l * 65536, Mph);
        if (l < 3) {
            (void)hipMemsetAsync(S, 0, 524288, stream);
            hipLaunchKernelGGL((layer_kernel<1>), dim3(BB * 64), dim3(256), 0, stream,
                               h, Wh + l * 4096, w_b + l * 64, Mph, basF, basI, S,
                               q_w, q_b, out);
        } else {
            hipLaunchKernelGGL((layer_kernel<0>), dim3(BB * 64), dim3(256), 0, stream,
                               h, Wh + l * 4096, w_b + l * 64, Mph, basF, basI, S,
                               q_w, q_b, out);
        }
    }
}